// Round 2
// baseline (5558.272 us; speedup 1.0000x reference)
//
#include <hip/hip_runtime.h>
#include <math.h>

#define B_N 4096
#define E_N 512
#define C_N 8
#define NU 64
#define BK 16
#define NDEPTH 8
#define MROWS 1536   // NU*BK + E_N
#define THR 0.001f
#define EPSV 1e-8f

// ---------------- build W^T : wt[f][m], f in [0,512), m in [0,1536) ----------
// rows m<1024: W[m][f] = sum_e basis[n][e][k] * H[e][f]  (n=m>>4, k=m&15)
// rows m>=1024: W[m][f] = H[m-1024][f]
__global__ void build_wt(const float* __restrict__ basis,
                         const float* __restrict__ hasher,
                         float* __restrict__ wt) {
  const int m = blockIdx.x;
  const int t = threadIdx.x;
  float a0, a1;
  if (m < NU * BK) {
    const int n = m >> 4, k = m & 15;
    const float* bp = basis + (size_t)n * E_N * BK + k;
    a0 = 0.f; a1 = 0.f;
    for (int e = 0; e < E_N; ++e) {
      const float bv = bp[(size_t)e * BK];
      const float* hrow = hasher + (size_t)e * E_N;
      a0 = fmaf(bv, hrow[t], a0);
      a1 = fmaf(bv, hrow[t + 256], a1);
    }
  } else {
    const int e = m - NU * BK;
    a0 = hasher[(size_t)e * E_N + t];
    a1 = hasher[(size_t)e * E_N + t + 256];
  }
  wt[(size_t)t * MROWS + m] = a0;
  wt[(size_t)(t + 256) * MROWS + m] = a1;
}

// ---------------- score kernel: z = W*r, reduce -> best[b] ------------------
#define SB 8      // samples per WG
#define NT 64     // cols per WG (= SB * C_N)
#define MT 256    // rows per M-tile
#define KT 16     // K per stage
#define NMT 6     // 1536/256 (tiles 0..3 = units, 4..5 = norm rows)
#define NKS 32    // 512/16

__launch_bounds__(256, 2)
__global__ void score_kernel(const float* __restrict__ r,
                             const float* __restrict__ wt,
                             const unsigned char* __restrict__ used,
                             int* __restrict__ best) {
  __shared__ __align__(16) float Ws[KT][MT];   // 16 KB
  __shared__ __align__(16) float Rs[KT][NT];   // 4 KB
  __shared__ __align__(16) float Sc[NU][NT];   // 16 KB  per-unit sum_k z^2
  __shared__ __align__(16) float Np[16][NT];   // 4 KB   norm partials per tu
  const int tid = threadIdx.x;
  const int tu = tid >> 4;    // 0..15 : owns rows tu*16..tu*16+15 of the tile
  const int tc = tid & 15;    // 0..15 : owns cols tc*4..tc*4+3
  const int bb = blockIdx.x * SB;
  const int sk = tid >> 4;    // staging: k row
  const int sch = tid & 15;   // staging: chunk
  const int ss = sch >> 1, sh = sch & 1;

  for (int mt = 0; mt < NMT; ++mt) {
    const int mbase = mt * MT;
    float acc[16][4];
#pragma unroll
    for (int i = 0; i < 16; ++i)
#pragma unroll
      for (int j = 0; j < 4; ++j) acc[i][j] = 0.f;

    for (int ks = 0; ks < NKS; ++ks) {
      const int kb = ks * KT;
      const float* wrow = wt + (size_t)(kb + sk) * MROWS + mbase + sch * 4;
      const float4 w0 = *(const float4*)(wrow);
      const float4 w1 = *(const float4*)(wrow + 64);
      const float4 w2 = *(const float4*)(wrow + 128);
      const float4 w3 = *(const float4*)(wrow + 192);
      const float4 rv = *(const float4*)(r + ((size_t)(bb + ss) * E_N + (kb + sk)) * C_N + sh * 4);
      __syncthreads();   // previous stage fully consumed
      *(float4*)&Ws[sk][sch * 4]       = w0;
      *(float4*)&Ws[sk][sch * 4 + 64]  = w1;
      *(float4*)&Ws[sk][sch * 4 + 128] = w2;
      *(float4*)&Ws[sk][sch * 4 + 192] = w3;
      *(float4*)&Rs[sk][ss * 8 + sh * 4] = rv;
      __syncthreads();
#pragma unroll
      for (int k = 0; k < KT; ++k) {
        float av[16];
        *(float4*)&av[0]  = *(const float4*)&Ws[k][tu * 16];
        *(float4*)&av[4]  = *(const float4*)&Ws[k][tu * 16 + 4];
        *(float4*)&av[8]  = *(const float4*)&Ws[k][tu * 16 + 8];
        *(float4*)&av[12] = *(const float4*)&Ws[k][tu * 16 + 12];
        float bv[4];
        *(float4*)&bv[0] = *(const float4*)&Rs[k][tc * 4];
#pragma unroll
        for (int i = 0; i < 16; ++i)
#pragma unroll
          for (int j = 0; j < 4; ++j)
            acc[i][j] = fmaf(av[i], bv[j], acc[i][j]);
      }
    }
    // deterministic thread-local reduction (each (row-group,col) has 1 owner)
    if (mbase < NU * BK) {
      const int u = (mbase >> 4) + tu;
#pragma unroll
      for (int j = 0; j < 4; ++j) {
        float s = 0.f;
#pragma unroll
        for (int i = 0; i < 16; ++i) s = fmaf(acc[i][j], acc[i][j], s);
        Sc[u][tc * 4 + j] = s;
      }
    } else {
#pragma unroll
      for (int j = 0; j < 4; ++j) {
        float s = 0.f;
#pragma unroll
        for (int i = 0; i < 16; ++i) s = fmaf(acc[i][j], acc[i][j], s);
        if (mt == 4) Np[tu][tc * 4 + j] = s;
        else         Np[tu][tc * 4 + j] += s;
      }
    }
  }
  __syncthreads();
  if (tid < SB) {
    const int b = bb + tid;
    float scale[C_N];
#pragma unroll
    for (int c = 0; c < C_N; ++c) {
      float nu = 0.f;
      for (int t16 = 0; t16 < 16; ++t16) nu += Np[t16][tid * 8 + c];
      const float inv = 1.f / (sqrtf(nu) + EPSV);
      scale[c] = inv * inv;
    }
    const unsigned char* ub = used + (size_t)b * NU;
    float bsv = -1.0f;  // scores are >= 0; matches first-max argmax semantics
    int bi = 0;
    for (int u = 0; u < NU; ++u) {
      if (ub[u]) continue;
      float s = 0.f;
#pragma unroll
      for (int c = 0; c < C_N; ++c) s = fmaf(Sc[u][tid * 8 + c], scale[c], s);
      if (s > bsv) { bsv = s; bi = u; }
    }
    best[b] = bi;
  }
}

// ---------------- update kernel: one WG per sample --------------------------
#define BSP 17   // padded stride for basis tile (kills 16-way bank conflict)

__launch_bounds__(256)
__global__ void update_kernel(const float* __restrict__ basis,
                              float* __restrict__ r,
                              const int* __restrict__ best,
                              unsigned char* __restrict__ used,
                              float* __restrict__ init_energy,
                              const int depth) {
  __shared__ __align__(16) float rs[E_N * C_N];     // 16 KB
  __shared__ __align__(16) float bsh[E_N * BSP];    // ~34.8 KB
  __shared__ __align__(16) float coeffs[BK * C_N];  // coeffs[k*8+c]
  __shared__ __align__(16) float part[2][BK * C_N];
  __shared__ __align__(16) float epart[256];
  const int b = blockIdx.x;
  const int tid = threadIdx.x;
  float* rb = r + (size_t)b * E_N * C_N;
  const int bu = best[b];
  const float* bp = basis + (size_t)bu * E_N * BK;

  float en = 0.f;
  for (int i = tid; i < E_N * C_N / 4; i += 256) {   // 4 iters
    const float4 v = ((const float4*)rb)[i];
    *(float4*)&rs[i * 4] = v;
    en = fmaf(v.x, v.x, en); en = fmaf(v.y, v.y, en);
    en = fmaf(v.z, v.z, en); en = fmaf(v.w, v.w, en);
  }
  for (int i = tid; i < E_N * BK / 4; i += 256) {    // 8 iters
    const float4 v = ((const float4*)bp)[i];
    const int f0 = i * 4;
    const int e = f0 >> 4, k = f0 & 15;
    bsh[e * BSP + k]     = v.x;
    bsh[e * BSP + k + 1] = v.y;
    bsh[e * BSP + k + 2] = v.z;
    bsh[e * BSP + k + 3] = v.w;
  }
  epart[tid] = en;
  __syncthreads();
  for (int s = 128; s > 0; s >>= 1) {   // deterministic tree reduce
    if (tid < s) epart[tid] += epart[tid + s];
    __syncthreads();
  }
  const float etot = epart[0];

  {  // coeffs[k,c] = sum_e bsel[e,k] * r[e,c], two halves then ordered combine
    const int p = tid & 127;
    const int k = p >> 3, c = p & 7;
    const int h = tid >> 7;
    const int e0 = h * 256;
    float s = 0.f;
    for (int e = e0; e < e0 + 256; ++e)
      s = fmaf(bsh[e * BSP + k], rs[e * 8 + c], s);
    part[h][p] = s;
  }
  __syncthreads();
  if (tid < 128) coeffs[tid] = part[0][tid] + part[1][tid];
  __syncthreads();

  float ie;
  if (depth == 0) {
    ie = etot;
    if (tid == 0) init_energy[b] = etot;
  } else {
    ie = init_energy[b];
  }
  const bool act = etot > THR * ie;
  if (act) {
#pragma unroll
    for (int q = 0; q < 4; ++q) {
      const int i4 = q * 256 + tid;         // float4 index in [0,1024)
      const int e = i4 >> 1, c0 = (i4 & 1) * 4;
      float p0 = 0.f, p1 = 0.f, p2 = 0.f, p3 = 0.f;
#pragma unroll
      for (int k = 0; k < BK; ++k) {
        const float bv = bsh[e * BSP + k];
        p0 = fmaf(bv, coeffs[k * 8 + c0], p0);
        p1 = fmaf(bv, coeffs[k * 8 + c0 + 1], p1);
        p2 = fmaf(bv, coeffs[k * 8 + c0 + 2], p2);
        p3 = fmaf(bv, coeffs[k * 8 + c0 + 3], p3);
      }
      float4 v = ((const float4*)rs)[i4];
      v.x -= p0; v.y -= p1; v.z -= p2; v.w -= p3;
      ((float4*)rb)[i4] = v;
    }
    if (tid == 0) used[(size_t)b * NU + bu] = 1;
  }
}

// ---------------- finalize: out = x - r_final -------------------------------
__global__ void finalize_kernel(const float* __restrict__ x,
                                const float* __restrict__ r,
                                float* __restrict__ out) {
  const int i = blockIdx.x * blockDim.x + threadIdx.x;
  const float4 xv = ((const float4*)x)[i];
  const float4 rv = ((const float4*)r)[i];
  float4 o;
  o.x = xv.x - rv.x; o.y = xv.y - rv.y;
  o.z = xv.z - rv.z; o.w = xv.w - rv.w;
  ((float4*)out)[i] = o;
}

extern "C" void kernel_launch(void* const* d_in, const int* in_sizes, int n_in,
                              void* d_out, int out_size, void* d_ws, size_t ws_size,
                              hipStream_t stream) {
  const float* x      = (const float*)d_in[0];
  const float* basis  = (const float*)d_in[1];
  const float* hasher = (const float*)d_in[2];
  float* out = (float*)d_out;

  // workspace layout (~70.6 MB)
  float* r           = (float*)d_ws;                       // 16,777,216 f
  float* wt          = r + (size_t)B_N * E_N * C_N;        //    786,432 f
  float* init_energy = wt + (size_t)E_N * MROWS;           //      4,096 f
  int*   best        = (int*)(init_energy + B_N);          //      4,096 i
  unsigned char* used = (unsigned char*)(best + B_N);      //    262,144 B

  hipMemcpyAsync(r, x, (size_t)B_N * E_N * C_N * sizeof(float),
                 hipMemcpyDeviceToDevice, stream);
  hipMemsetAsync(used, 0, (size_t)B_N * NU, stream);
  build_wt<<<MROWS, 256, 0, stream>>>(basis, hasher, wt);

  for (int d = 0; d < NDEPTH; ++d) {
    score_kernel<<<B_N / SB, 256, 0, stream>>>(r, wt, used, best);
    update_kernel<<<B_N, 256, 0, stream>>>(basis, r, best, used, init_energy, d);
  }
  finalize_kernel<<<(B_N * E_N * C_N / 4) / 256, 256, 0, stream>>>(x, r, out);
}